// Round 1
// baseline (1532.558 us; speedup 1.0000x reference)
//
#include <hip/hip_runtime.h>

#define E_EXP 32
#define TK 6144           // T*K pairs
#define HD 2048
#define FD 1408
#define MT 64
#define MAXROWS 8192
#define MAXMB 128
#define LDA 40            // LDS row stride in shorts (32 + 8 pad, keeps 16B align)

typedef short bf16x8 __attribute__((ext_vector_type(8)));
typedef float f32x4  __attribute__((ext_vector_type(4)));
typedef unsigned short u16;

__device__ __forceinline__ u16 f2bf(float f) {
  unsigned u = __float_as_uint(f);
  u += 0x7FFFu + ((u >> 16) & 1u);   // RNE
  return (u16)(u >> 16);
}

// ---------------- routing: histogram -> padded per-expert segments ----------
__global__ __launch_bounds__(256) void routing_kernel(
    const int* __restrict__ ids, const float* __restrict__ tw,
    int* __restrict__ ptok, float* __restrict__ pw,
    int* __restrict__ bexp, int* __restrict__ hdr)
{
  __shared__ int cnt[E_EXP], off[E_EXP], fill[E_EXP], total_s[1];
  int tid = threadIdx.x;
  if (tid < E_EXP) { cnt[tid] = 0; fill[tid] = 0; }
  __syncthreads();
  for (int i = tid; i < TK; i += 256) atomicAdd(&cnt[ids[i]], 1);
  __syncthreads();
  if (tid == 0) {
    int run = 0, mb = 0;
    for (int e = 0; e < E_EXP; e++) {
      off[e] = run;
      int nb = (cnt[e] + MT - 1) / MT;
      for (int b = 0; b < nb; b++) bexp[mb++] = e;
      run += nb * MT;
    }
    total_s[0] = run;
    hdr[0] = mb;     // number of m-blocks
    hdr[1] = run;    // total padded rows
  }
  __syncthreads();
  int total = total_s[0];
  for (int i = tid; i < total; i += 256) { ptok[i] = 0; pw[i] = 0.f; }
  __syncthreads();
  for (int i = tid; i < TK; i += 256) {
    int e = ids[i];
    int pos = off[e] + atomicAdd(&fill[e], 1);
    ptok[pos] = i / 6;          // token index (row-major (T,K))
    pw[pos]   = tw[i];
  }
}

// ---------------- x fp32 -> bf16 --------------------------------------------
__global__ __launch_bounds__(256) void xcvt_kernel(
    const float* __restrict__ x, u16* __restrict__ xbf)
{
  int i = (blockIdx.x * 256 + threadIdx.x) * 4;
  float4 v = *(const float4*)(x + i);
  u16 o0 = f2bf(v.x), o1 = f2bf(v.y), o2 = f2bf(v.z), o3 = f2bf(v.w);
  ushort4 o; o.x = o0; o.y = o1; o.z = o2; o.w = o3;
  *(ushort4*)(xbf + i) = o;
}

// ---------------- GEMM1: gu = x @ Wgu^T, SwiGLU -> h (bf16) -----------------
// grid: (MAXMB, FD/64). Block 256 thr = 4 waves, tile 64 rows x (64 gate + 64 up).
__global__ __launch_bounds__(256) void gemm1_kernel(
    const u16* __restrict__ xbf, const float* __restrict__ wgu,
    const int* __restrict__ ptok, const int* __restrict__ bexp,
    const int* __restrict__ hdr, u16* __restrict__ hout)
{
  int mb = blockIdx.x;
  if (mb >= hdr[0]) return;
  int e    = bexp[mb];
  int row0 = mb * MT;
  int n0   = blockIdx.y * 64;   // f-tile base, [0, FD)

  __shared__ int tok[MT];
  __shared__ u16 Al[MT * LDA];
  __shared__ u16 Bl[128 * LDA];

  int tid = threadIdx.x;
  if (tid < MT) tok[tid] = ptok[row0 + tid];
  __syncthreads();

  // staging coords
  int ar = tid >> 2, ac = (tid & 3) * 8;          // A: 64 rows x 32k, 8 bf16/thr
  int br = tid >> 1, bc = (tid & 1) * 16;         // B: 128 rows x 32k, 16 f32/thr
  int wrow = (br < 64) ? (n0 + br) : (FD + n0 + (br - 64));
  const float* bptr = wgu + ((size_t)e * (2 * FD) + wrow) * HD + bc;
  const u16*   aptr = xbf + (size_t)tok[ar] * HD + ac;

  int wave = tid >> 6, lane = tid & 63;
  int wm = wave >> 1, wn = wave & 1;
  int quad = lane >> 4, l15 = lane & 15;
  int koff = quad * 8;

  f32x4 accg[2][2], accu[2][2];
  for (int i = 0; i < 2; i++)
    for (int j = 0; j < 2; j++) {
      accg[i][j] = (f32x4){0.f, 0.f, 0.f, 0.f};
      accu[i][j] = (f32x4){0.f, 0.f, 0.f, 0.f};
    }

  for (int k0 = 0; k0 < HD; k0 += 32) {
    bf16x8 av = *(const bf16x8*)(aptr + k0);
    float4 b0 = *(const float4*)(bptr + k0);
    float4 b1 = *(const float4*)(bptr + k0 + 4);
    float4 b2 = *(const float4*)(bptr + k0 + 8);
    float4 b3 = *(const float4*)(bptr + k0 + 12);
    __syncthreads();
    *(bf16x8*)&Al[ar * LDA + ac] = av;
    bf16x8 bv0, bv1;
    bv0[0] = (short)f2bf(b0.x); bv0[1] = (short)f2bf(b0.y);
    bv0[2] = (short)f2bf(b0.z); bv0[3] = (short)f2bf(b0.w);
    bv0[4] = (short)f2bf(b1.x); bv0[5] = (short)f2bf(b1.y);
    bv0[6] = (short)f2bf(b1.z); bv0[7] = (short)f2bf(b1.w);
    bv1[0] = (short)f2bf(b2.x); bv1[1] = (short)f2bf(b2.y);
    bv1[2] = (short)f2bf(b2.z); bv1[3] = (short)f2bf(b2.w);
    bv1[4] = (short)f2bf(b3.x); bv1[5] = (short)f2bf(b3.y);
    bv1[6] = (short)f2bf(b3.z); bv1[7] = (short)f2bf(b3.w);
    *(bf16x8*)&Bl[br * LDA + bc]     = bv0;
    *(bf16x8*)&Bl[br * LDA + bc + 8] = bv1;
    __syncthreads();

    bf16x8 af0 = *(const bf16x8*)&Al[(wm * 32 + l15)      * LDA + koff];
    bf16x8 af1 = *(const bf16x8*)&Al[(wm * 32 + 16 + l15) * LDA + koff];
    bf16x8 bg0 = *(const bf16x8*)&Bl[(wn * 32 + l15)      * LDA + koff];
    bf16x8 bg1 = *(const bf16x8*)&Bl[(wn * 32 + 16 + l15) * LDA + koff];
    bf16x8 bu0 = *(const bf16x8*)&Bl[(64 + wn * 32 + l15)      * LDA + koff];
    bf16x8 bu1 = *(const bf16x8*)&Bl[(64 + wn * 32 + 16 + l15) * LDA + koff];

    accg[0][0] = __builtin_amdgcn_mfma_f32_16x16x32_bf16(af0, bg0, accg[0][0], 0, 0, 0);
    accg[0][1] = __builtin_amdgcn_mfma_f32_16x16x32_bf16(af0, bg1, accg[0][1], 0, 0, 0);
    accg[1][0] = __builtin_amdgcn_mfma_f32_16x16x32_bf16(af1, bg0, accg[1][0], 0, 0, 0);
    accg[1][1] = __builtin_amdgcn_mfma_f32_16x16x32_bf16(af1, bg1, accg[1][1], 0, 0, 0);
    accu[0][0] = __builtin_amdgcn_mfma_f32_16x16x32_bf16(af0, bu0, accu[0][0], 0, 0, 0);
    accu[0][1] = __builtin_amdgcn_mfma_f32_16x16x32_bf16(af0, bu1, accu[0][1], 0, 0, 0);
    accu[1][0] = __builtin_amdgcn_mfma_f32_16x16x32_bf16(af1, bu0, accu[1][0], 0, 0, 0);
    accu[1][1] = __builtin_amdgcn_mfma_f32_16x16x32_bf16(af1, bu1, accu[1][1], 0, 0, 0);
  }

  // epilogue: h = silu(gate) * up, store bf16
  for (int i = 0; i < 2; i++)
    for (int j = 0; j < 2; j++)
      for (int r = 0; r < 4; r++) {
        int rl = wm * 32 + i * 16 + quad * 4 + r;
        int cl = wn * 32 + j * 16 + l15;
        float g = accg[i][j][r];
        float u = accu[i][j][r];
        float s = g / (1.f + __expf(-g));
        hout[(size_t)(row0 + rl) * FD + (n0 + cl)] = f2bf(s * u);
      }
}

// ---------------- GEMM2: y = h @ Wd^T, weighted scatter-add -----------------
// grid: (MAXMB, HD/64). Block 256 thr, tile 64 x 64.
__global__ __launch_bounds__(256) void gemm2_kernel(
    const u16* __restrict__ hin, const float* __restrict__ wd,
    const int* __restrict__ ptok, const float* __restrict__ pwg,
    const int* __restrict__ bexp, const int* __restrict__ hdr,
    float* __restrict__ out)
{
  int mb = blockIdx.x;
  if (mb >= hdr[0]) return;
  int e    = bexp[mb];
  int row0 = mb * MT;
  int n0   = blockIdx.y * 64;   // h'-tile base in [0, HD)

  __shared__ int   tokl[MT];
  __shared__ float pwl[MT];
  __shared__ u16 Al[MT * LDA];
  __shared__ u16 Bl[MT * LDA];

  int tid = threadIdx.x;
  if (tid < MT) { tokl[tid] = ptok[row0 + tid]; pwl[tid] = pwg[row0 + tid]; }

  int ar = tid >> 2, ac = (tid & 3) * 8;        // A: 64 x 32, 8 bf16/thr
  int brr = tid >> 2, bcc = (tid & 3) * 8;      // B: 64 x 32, 8 f32/thr
  const u16*   aptr = hin + (size_t)(row0 + ar) * FD + ac;
  const float* bptr = wd + ((size_t)e * HD + (n0 + brr)) * FD + bcc;

  int wave = tid >> 6, lane = tid & 63;
  int wm = wave >> 1, wn = wave & 1;
  int quad = lane >> 4, l15 = lane & 15;
  int koff = quad * 8;

  f32x4 acc[2][2];
  for (int i = 0; i < 2; i++)
    for (int j = 0; j < 2; j++) acc[i][j] = (f32x4){0.f, 0.f, 0.f, 0.f};

  for (int k0 = 0; k0 < FD; k0 += 32) {
    bf16x8 av = *(const bf16x8*)(aptr + k0);
    float4 b0 = *(const float4*)(bptr + k0);
    float4 b1 = *(const float4*)(bptr + k0 + 4);
    __syncthreads();
    *(bf16x8*)&Al[ar * LDA + ac] = av;
    bf16x8 bv;
    bv[0] = (short)f2bf(b0.x); bv[1] = (short)f2bf(b0.y);
    bv[2] = (short)f2bf(b0.z); bv[3] = (short)f2bf(b0.w);
    bv[4] = (short)f2bf(b1.x); bv[5] = (short)f2bf(b1.y);
    bv[6] = (short)f2bf(b1.z); bv[7] = (short)f2bf(b1.w);
    *(bf16x8*)&Bl[brr * LDA + bcc] = bv;
    __syncthreads();

    bf16x8 af0 = *(const bf16x8*)&Al[(wm * 32 + l15)      * LDA + koff];
    bf16x8 af1 = *(const bf16x8*)&Al[(wm * 32 + 16 + l15) * LDA + koff];
    bf16x8 bf0 = *(const bf16x8*)&Bl[(wn * 32 + l15)      * LDA + koff];
    bf16x8 bf1 = *(const bf16x8*)&Bl[(wn * 32 + 16 + l15) * LDA + koff];

    acc[0][0] = __builtin_amdgcn_mfma_f32_16x16x32_bf16(af0, bf0, acc[0][0], 0, 0, 0);
    acc[0][1] = __builtin_amdgcn_mfma_f32_16x16x32_bf16(af0, bf1, acc[0][1], 0, 0, 0);
    acc[1][0] = __builtin_amdgcn_mfma_f32_16x16x32_bf16(af1, bf0, acc[1][0], 0, 0, 0);
    acc[1][1] = __builtin_amdgcn_mfma_f32_16x16x32_bf16(af1, bf1, acc[1][1], 0, 0, 0);
  }

  for (int i = 0; i < 2; i++)
    for (int r = 0; r < 4; r++) {
      int rl = wm * 32 + i * 16 + quad * 4 + r;
      float w = pwl[rl];
      if (w != 0.f) {
        int t = tokl[rl];
        for (int j = 0; j < 2; j++) {
          int cl = wn * 32 + j * 16 + l15;
          atomicAdd(&out[(size_t)t * HD + (n0 + cl)], acc[i][j][r] * w);
        }
      }
    }
}

// ---------------------------------------------------------------------------
extern "C" void kernel_launch(void* const* d_in, const int* in_sizes, int n_in,
                              void* d_out, int out_size, void* d_ws, size_t ws_size,
                              hipStream_t stream) {
  const float* x   = (const float*)d_in[0];
  const float* wgu = (const float*)d_in[1];
  const float* wd  = (const float*)d_in[2];
  const float* tw  = (const float*)d_in[3];
  const int*   ids = (const int*)d_in[4];
  float* out = (float*)d_out;

  char* ws = (char*)d_ws;
  int*   hdr  = (int*)ws;                   // 16 ints
  int*   ptok = (int*)(ws + 64);            // 8192 ints
  float* pw   = (float*)(ws + 32832);       // 8192 floats
  int*   bexp = (int*)(ws + 65600);         // 128 ints
  u16*   xbf  = (u16*)(ws + 66560);         // 1024*2048 bf16 (4 MB)
  u16*   hbuf = (u16*)(ws + 4260864);       // 8192*1408 bf16 (23 MB)

  hipMemsetAsync(d_out, 0, (size_t)out_size * sizeof(float), stream);

  routing_kernel<<<1, 256, 0, stream>>>(ids, tw, ptok, pw, bexp, hdr);
  xcvt_kernel<<<2048, 256, 0, stream>>>(x, xbf);
  gemm1_kernel<<<dim3(MAXMB, FD / 64), 256, 0, stream>>>(xbf, wgu, ptok, bexp, hdr, hbuf);
  gemm2_kernel<<<dim3(MAXMB, HD / 64), 256, 0, stream>>>(hbuf, wd, ptok, pw, bexp, hdr, out);
}